// Round 1
// baseline (942.468 us; speedup 1.0000x reference)
//
#include <hip/hip_runtime.h>

#define NN 200000
#define NE 600000
#define NG 1024
#define HH 512

typedef short short8 __attribute__((ext_vector_type(8)));
typedef float f32x4 __attribute__((ext_vector_type(4)));

__device__ __forceinline__ unsigned short f2bf(float f){
  unsigned u = __float_as_uint(f);
  u += 0x7fffu + ((u >> 16) & 1u);
  return (unsigned short)(u >> 16);
}

// gelu(x) = x * sigmoid(1.5957691216*x + 0.07135481627*x^3)  (== tanh-form GELU, max |err| ~5e-4)
__device__ __forceinline__ float gelu_f(float x){
  float p = __builtin_fmaf(x*x, -0.07135481627f, -1.5957691216f);
  float e = __expf(x * p);              // e^{-2u}
  return x * __builtin_amdgcn_rcpf(1.0f + e);
}

// ---------------- histogram / counting sort ----------------
__global__ void khist_node(const int* __restrict__ bidx, int* __restrict__ cntn){
  int i = blockIdx.x*256 + threadIdx.x;
  if (i < NN) atomicAdd(&cntn[bidx[i]], 1);
}
__global__ void khist_edge(const int* __restrict__ bidx, const int* __restrict__ eidx,
                           int* __restrict__ eg, int* __restrict__ cnte){
  int e = blockIdx.x*256 + threadIdx.x;
  if (e < NE){ int g = bidx[eidx[e]]; eg[e] = g; atomicAdd(&cnte[g], 1); }
}
__global__ void kscan(const int* __restrict__ cnte, int* __restrict__ cursor){
  __shared__ int s[NG];
  int t = threadIdx.x;
  int v = cnte[t]; s[t] = v; __syncthreads();
  for (int d=1; d<NG; d<<=1){
    int x = (t>=d) ? s[t-d] : 0;
    __syncthreads();
    s[t] += x;
    __syncthreads();
  }
  cursor[t] = s[t] - v;   // exclusive prefix
}
__global__ void kscatter(const int* __restrict__ eg, int* __restrict__ cursor,
                         int* __restrict__ perm, int* __restrict__ sg){
  int e = blockIdx.x*256 + threadIdx.x;
  if (e < NE){ int g = eg[e]; int p = atomicAdd(&cursor[g], 1); perm[p] = e; sg[p] = g; }
}

// ---------------- weight prep: fold BN into first-layer weights, bf16 B^T layout ----------------
__global__ void kprep(const float* __restrict__ nfw1, const float* __restrict__ nfb1,
                      const float* __restrict__ nfg1, const float* __restrict__ nfbe1,
                      const float* __restrict__ efw1, const float* __restrict__ efb1,
                      const float* __restrict__ efg1, const float* __restrict__ efbe1,
                      unsigned short* __restrict__ w1nT, unsigned short* __restrict__ w1eT,
                      float* __restrict__ b1n, float* __restrict__ b1e){
  int c = blockIdx.x*64 + threadIdx.x;
  if (c >= HH) return;
  const float rs = 0.99999500003750f;     // 1/sqrt(1+1e-5)
  float sn = nfg1[c]*rs, se = efg1[c]*rs;
  for (int k=0;k<64;k++){                 // rows 0..31: nf features, 32..40: one-hot rows, rest 0
    float w = (k < 41) ? nfw1[k*HH + c]*sn : 0.0f;
    w1nT[c*64 + k] = f2bf(w);
  }
  for (int k=0;k<32;k++){
    float w = (k < 16) ? efw1[k*HH + c]*se : 0.0f;
    w1eT[c*32 + k] = f2bf(w);
  }
  b1n[c] = nfb1[c]*sn + nfbe1[c];
  b1e[c] = efb1[c]*se + efbe1[c];
}

// ---------------- node first layer: MFMA + gelu + sorted segment-sum ----------------
__global__ __launch_bounds__(256) void knode(const float* __restrict__ nf, const float* __restrict__ dp,
    const int* __restrict__ ny, const int* __restrict__ bidx,
    const unsigned short* __restrict__ w1nT, const float* __restrict__ b1n, float* __restrict__ Sn){
  const int lane = threadIdx.x & 63, wv = threadIdx.x >> 6;
  const int q = lane >> 4, m = lane & 15;
  const int r0 = blockIdx.x*256 + wv*64;
  short8 a0[4], a1[4];
  int4 g4[4];
  int gfi[4]; bool tok[4];
  const short8 zz = {0,0,0,0,0,0,0,0};
#pragma unroll
  for (int rt=0; rt<4; ++rt){
    int rb = r0 + rt*16;
    int row = rb + m;
    bool valid = row < NN;
    int ar = valid ? row : (NN-1);
    const float4* ap = (const float4*)(nf + (size_t)ar*32 + q*8);
    float4 xa = ap[0], xb = ap[1];
    short8 f;
    f[0]=(short)f2bf(xa.x); f[1]=(short)f2bf(xa.y); f[2]=(short)f2bf(xa.z); f[3]=(short)f2bf(xa.w);
    f[4]=(short)f2bf(xb.x); f[5]=(short)f2bf(xb.y); f[6]=(short)f2bf(xb.z); f[7]=(short)f2bf(xb.w);
    if (!valid) f = zz;
    a0[rt] = f;
    int cls = ny[ar];
    short dpb = (short)f2bf(dp[ar]);
    short8 h = zz;
    if (valid){
      if (q == 0){
#pragma unroll
        for (int j=0;j<8;++j) h[j] = (cls==j) ? dpb : (short)0;
      } else if (q == 1 && cls == 8) h[0] = dpb;
    }
    a1[rt] = h;
    int gb = rb + q*4;
    if (gb + 3 < NN) g4[rt] = *(const int4*)(bidx + gb);
    else {
      g4[rt].x = (gb   < NN) ? bidx[gb  ] : -1;
      g4[rt].y = (gb+1 < NN) ? bidx[gb+1] : -1;
      g4[rt].z = (gb+2 < NN) ? bidx[gb+2] : -1;
      g4[rt].w = (gb+3 < NN) ? bidx[gb+3] : -1;
    }
    int gA = bidx[min(rb, NN-1)], gB = bidx[min(rb+15, NN-1)];
    tok[rt] = (rb + 15 < NN) && (gA == gB);   // batch_idx sorted -> first==last => uniform
    gfi[rt] = gA;
  }
  int gW = bidx[min(r0, NN-1)];
  bool wok = (r0 + 63 < NN) && (gW == bidx[min(r0+63, NN-1)]);

  for (int nt=0; nt<32; ++nt){
    const short8* bp = (const short8*)(w1nT + ((nt*16 + m) << 6) + (q << 3));
    short8 b0 = bp[0];
    short8 b1 = bp[4];                     // +32 shorts: k=32..63 chunk (one-hot rows)
    float bias = b1n[(nt<<4) + m];
    float wsum = 0.0f;
#pragma unroll
    for (int rt=0; rt<4; ++rt){
      f32x4 acc = {0.f,0.f,0.f,0.f};
      acc = __builtin_amdgcn_mfma_f32_16x16x32_bf16(a0[rt], b0, acc, 0, 0, 0);
      acc = __builtin_amdgcn_mfma_f32_16x16x32_bf16(a1[rt], b1, acc, 0, 0, 0);
      float v0 = gelu_f(acc[0] + bias);
      float v1 = gelu_f(acc[1] + bias);
      float v2 = gelu_f(acc[2] + bias);
      float v3 = gelu_f(acc[3] + bias);
      if (wok){
        wsum += (v0+v1)+(v2+v3);
      } else if (tok[rt]){
        float ts = (v0+v1)+(v2+v3);
        ts += __shfl_xor(ts, 16);
        ts += __shfl_xor(ts, 32);
        if (lane < 16) unsafeAtomicAdd(&Sn[(size_t)gfi[rt]*HH + (nt<<4) + lane], ts);
      } else {
        int cb = (nt<<4) + m;
        if (g4[rt].x >= 0) unsafeAtomicAdd(&Sn[(size_t)g4[rt].x*HH + cb], v0);
        if (g4[rt].y >= 0) unsafeAtomicAdd(&Sn[(size_t)g4[rt].y*HH + cb], v1);
        if (g4[rt].z >= 0) unsafeAtomicAdd(&Sn[(size_t)g4[rt].z*HH + cb], v2);
        if (g4[rt].w >= 0) unsafeAtomicAdd(&Sn[(size_t)g4[rt].w*HH + cb], v3);
      }
    }
    if (wok){
      wsum += __shfl_xor(wsum, 16);
      wsum += __shfl_xor(wsum, 32);
      if (lane < 16) unsafeAtomicAdd(&Sn[(size_t)gW*HH + (nt<<4) + lane], wsum);
    }
  }
}

// ---------------- edge first layer (sorted by graph via perm/sg) ----------------
__global__ __launch_bounds__(256) void kedge(const float* __restrict__ ef, const int* __restrict__ perm,
    const int* __restrict__ sg, const unsigned short* __restrict__ w1eT, const float* __restrict__ b1e,
    float* __restrict__ Se){
  const int lane = threadIdx.x & 63, wv = threadIdx.x >> 6;
  const int q = lane >> 4, m = lane & 15;
  const int r0 = blockIdx.x*256 + wv*64;
  short8 a0[4];
  int4 g4[4];
  int gfi[4]; bool tok[4];
  const short8 zz = {0,0,0,0,0,0,0,0};
#pragma unroll
  for (int rt=0; rt<4; ++rt){
    int rb = r0 + rt*16;
    int row = rb + m;
    bool valid = row < NE;
    int e = perm[valid ? row : (NE-1)];
    short8 f = zz;
    if (valid && q < 2){
      const float4* ap = (const float4*)(ef + (size_t)e*16 + q*8);
      float4 xa = ap[0], xb = ap[1];
      f[0]=(short)f2bf(xa.x); f[1]=(short)f2bf(xa.y); f[2]=(short)f2bf(xa.z); f[3]=(short)f2bf(xa.w);
      f[4]=(short)f2bf(xb.x); f[5]=(short)f2bf(xb.y); f[6]=(short)f2bf(xb.z); f[7]=(short)f2bf(xb.w);
    }
    a0[rt] = f;
    int gb = rb + q*4;
    if (gb + 3 < NE) g4[rt] = *(const int4*)(sg + gb);
    else {
      g4[rt].x = (gb   < NE) ? sg[gb  ] : -1;
      g4[rt].y = (gb+1 < NE) ? sg[gb+1] : -1;
      g4[rt].z = (gb+2 < NE) ? sg[gb+2] : -1;
      g4[rt].w = (gb+3 < NE) ? sg[gb+3] : -1;
    }
    int gA = sg[min(rb, NE-1)], gB = sg[min(rb+15, NE-1)];
    tok[rt] = (rb + 15 < NE) && (gA == gB);
    gfi[rt] = gA;
  }
  int gW = sg[min(r0, NE-1)];
  bool wok = (r0 + 63 < NE) && (gW == sg[min(r0+63, NE-1)]);

  for (int nt=0; nt<32; ++nt){
    short8 b0 = *(const short8*)(w1eT + ((nt*16 + m) << 5) + (q << 3));
    float bias = b1e[(nt<<4) + m];
    float wsum = 0.0f;
#pragma unroll
    for (int rt=0; rt<4; ++rt){
      f32x4 acc = {0.f,0.f,0.f,0.f};
      acc = __builtin_amdgcn_mfma_f32_16x16x32_bf16(a0[rt], b0, acc, 0, 0, 0);
      float v0 = gelu_f(acc[0] + bias);
      float v1 = gelu_f(acc[1] + bias);
      float v2 = gelu_f(acc[2] + bias);
      float v3 = gelu_f(acc[3] + bias);
      if (wok){
        wsum += (v0+v1)+(v2+v3);
      } else if (tok[rt]){
        float ts = (v0+v1)+(v2+v3);
        ts += __shfl_xor(ts, 16);
        ts += __shfl_xor(ts, 32);
        if (lane < 16) unsafeAtomicAdd(&Se[(size_t)gfi[rt]*HH + (nt<<4) + lane], ts);
      } else {
        int cb = (nt<<4) + m;
        if (g4[rt].x >= 0) unsafeAtomicAdd(&Se[(size_t)g4[rt].x*HH + cb], v0);
        if (g4[rt].y >= 0) unsafeAtomicAdd(&Se[(size_t)g4[rt].y*HH + cb], v1);
        if (g4[rt].z >= 0) unsafeAtomicAdd(&Se[(size_t)g4[rt].z*HH + cb], v2);
        if (g4[rt].w >= 0) unsafeAtomicAdd(&Se[(size_t)g4[rt].w*HH + cb], v3);
      }
    }
    if (wok){
      wsum += __shfl_xor(wsum, 16);
      wsum += __shfl_xor(wsum, 32);
      if (lane < 16) unsafeAtomicAdd(&Se[(size_t)gW*HH + (nt<<4) + lane], wsum);
    }
  }
}

// ---------------- finish GEMMs (1024x512 @ 512x512), fp32, fused epilogues ----------------
// mode 0: out = C + gf + cntn*b2n + cnte*b2e
// mode 1: out = C + out
// mode 2: out = gelu((C + bias)*gam*rs + bet)
__global__ __launch_bounds__(256) void kgemm(const float* __restrict__ A, const float* __restrict__ B,
    float* __restrict__ out, int mode,
    const float* __restrict__ gf, const int* __restrict__ cntn, const int* __restrict__ cnte,
    const float* __restrict__ b2n, const float* __restrict__ b2e,
    const float* __restrict__ bias, const float* __restrict__ gam, const float* __restrict__ bet){
  __shared__ float Ast[16*68];   // A^T tile: [k][row], padded
  __shared__ float Bs[16*68];    // B tile:   [k][col], padded
  const int t = threadIdx.x, tx = t & 15, ty = t >> 4;
  const int c0 = blockIdx.x*64, r0 = blockIdx.y*64;
  float acc[4][4] = {};
  for (int ks=0; ks<32; ++ks){
    const int k0 = ks*16;
#pragma unroll
    for (int u=0; u<4; ++u){
      int ff = t + u*256;
      Ast[(ff & 15)*68 + (ff >> 4)] = A[(size_t)(r0 + (ff >> 4))*HH + k0 + (ff & 15)];
      Bs[(ff >> 6)*68 + (ff & 63)] = B[(size_t)(k0 + (ff >> 6))*HH + c0 + (ff & 63)];
    }
    __syncthreads();
#pragma unroll
    for (int k=0;k<16;++k){
      float4 a4 = *(const float4*)&Ast[k*68 + ty*4];
      float4 b4 = *(const float4*)&Bs[k*68 + tx*4];
      float av[4] = {a4.x, a4.y, a4.z, a4.w};
      float bv[4] = {b4.x, b4.y, b4.z, b4.w};
#pragma unroll
      for (int i=0;i<4;++i)
#pragma unroll
        for (int j=0;j<4;++j) acc[i][j] = __builtin_fmaf(av[i], bv[j], acc[i][j]);
    }
    __syncthreads();
  }
  const int r = r0 + ty*4, c = c0 + tx*4;
  if (mode == 0){
    float4 bn4 = *(const float4*)&b2n[c];
    float4 be4 = *(const float4*)&b2e[c];
#pragma unroll
    for (int i=0;i<4;++i){
      float4 gv = *(const float4*)&gf[(size_t)(r+i)*HH + c];
      float cn = (float)cntn[r+i], ce = (float)cnte[r+i];
      float4 o;
      o.x = acc[i][0] + gv.x + cn*bn4.x + ce*be4.x;
      o.y = acc[i][1] + gv.y + cn*bn4.y + ce*be4.y;
      o.z = acc[i][2] + gv.z + cn*bn4.z + ce*be4.z;
      o.w = acc[i][3] + gv.w + cn*bn4.w + ce*be4.w;
      *(float4*)&out[(size_t)(r+i)*HH + c] = o;
    }
  } else if (mode == 1){
#pragma unroll
    for (int i=0;i<4;++i){
      float4 pv = *(const float4*)&out[(size_t)(r+i)*HH + c];
      float4 o;
      o.x = acc[i][0] + pv.x; o.y = acc[i][1] + pv.y;
      o.z = acc[i][2] + pv.z; o.w = acc[i][3] + pv.w;
      *(float4*)&out[(size_t)(r+i)*HH + c] = o;
    }
  } else {
    const float rs = 0.99999500003750f;
    float4 ga = *(const float4*)&gam[c];
    float4 bi = *(const float4*)&bias[c];
    float4 be = *(const float4*)&bet[c];
    float s0 = ga.x*rs, s1 = ga.y*rs, s2 = ga.z*rs, s3 = ga.w*rs;
#pragma unroll
    for (int i=0;i<4;++i){
      float4 o;
      o.x = gelu_f((acc[i][0] + bi.x)*s0 + be.x);
      o.y = gelu_f((acc[i][1] + bi.y)*s1 + be.y);
      o.z = gelu_f((acc[i][2] + bi.z)*s2 + be.z);
      o.w = gelu_f((acc[i][3] + bi.w)*s3 + be.w);
      *(float4*)&out[(size_t)(r+i)*HH + c] = o;
    }
  }
}

// ---------------- final 512 -> 2 linear ----------------
__global__ __launch_bounds__(256) void kfinal(const float* __restrict__ x2, const float* __restrict__ w3,
    const float* __restrict__ b3, float* __restrict__ out){
  const int lane = threadIdx.x & 63, wv = threadIdx.x >> 6;
  const int r = blockIdx.x*4 + wv;
  float a0 = 0.f, a1 = 0.f;
#pragma unroll
  for (int tt=0; tt<8; ++tt){
    int k = lane + tt*64;
    float x = x2[(size_t)r*HH + k];
    a0 = __builtin_fmaf(x, w3[2*k], a0);
    a1 = __builtin_fmaf(x, w3[2*k+1], a1);
  }
#pragma unroll
  for (int d=1; d<64; d<<=1){ a0 += __shfl_xor(a0, d); a1 += __shfl_xor(a1, d); }
  if (lane == 0){ out[r*2] = a0 + b3[0]; out[r*2+1] = a1 + b3[1]; }
}

extern "C" void kernel_launch(void* const* d_in, const int* in_sizes, int n_in,
                              void* d_out, int out_size, void* d_ws, size_t ws_size,
                              hipStream_t stream) {
  const float* nf    = (const float*)d_in[0];
  const float* ef    = (const float*)d_in[1];
  const float* gf    = (const float*)d_in[2];
  const float* dp    = (const float*)d_in[3];
  const int*   ny    = (const int*)d_in[4];
  const int*   bidx  = (const int*)d_in[5];
  const int*   eidx  = (const int*)d_in[6];
  const float* nfw1  = (const float*)d_in[7];
  const float* nfb1  = (const float*)d_in[8];
  const float* nfg1  = (const float*)d_in[9];
  const float* nfbe1 = (const float*)d_in[10];
  const float* w2n   = (const float*)d_in[11];
  const float* b2n   = (const float*)d_in[12];
  const float* efw1  = (const float*)d_in[13];
  const float* efb1  = (const float*)d_in[14];
  const float* efg1  = (const float*)d_in[15];
  const float* efbe1 = (const float*)d_in[16];
  const float* w2e   = (const float*)d_in[17];
  const float* b2e   = (const float*)d_in[18];
  const float* ow1   = (const float*)d_in[19];
  const float* ob1   = (const float*)d_in[20];
  const float* og1   = (const float*)d_in[21];
  const float* obe1  = (const float*)d_in[22];
  const float* ow2   = (const float*)d_in[23];
  const float* ob2   = (const float*)d_in[24];
  const float* og2   = (const float*)d_in[25];
  const float* obe2  = (const float*)d_in[26];
  const float* ow3   = (const float*)d_in[27];
  const float* ob3   = (const float*)d_in[28];

  // workspace carve
  float* Sn = (float*)d_ws;                   // 1024*512
  float* Se = Sn + NG*HH;                     // 1024*512
  int* cntn = (int*)(Se + NG*HH);             // 1024
  int* cnte = cntn + NG;                      // 1024
  int* cursor = cnte + NG;                    // 1024
  int* eg   = cursor + NG;                    // NE
  int* perm = eg + NE;                        // NE
  int* sg   = perm + NE;                      // NE
  unsigned short* w1nT = (unsigned short*)(sg + NE);  // 512*64
  unsigned short* w1eT = w1nT + HH*64;                // 512*32
  float* b1n = (float*)(w1eT + HH*32);        // 512
  float* b1e = b1n + HH;                      // 512
  float* gh  = b1e + HH;                      // 1024*512
  float* x1  = gh + NG*HH;                    // 1024*512
  float* x2  = x1 + NG*HH;                    // 1024*512

  // zero accumulators + counters (ws is poisoned 0xAA before every call)
  size_t zbytes = (size_t)(2*NG*HH + 3*NG) * sizeof(int);
  hipMemsetAsync(d_ws, 0, zbytes, stream);

  kprep<<<8, 64, 0, stream>>>(nfw1, nfb1, nfg1, nfbe1, efw1, efb1, efg1, efbe1,
                              w1nT, w1eT, b1n, b1e);
  khist_node<<<(NN+255)/256, 256, 0, stream>>>(bidx, cntn);
  khist_edge<<<(NE+255)/256, 256, 0, stream>>>(bidx, eidx, eg, cnte);
  kscan<<<1, NG, 0, stream>>>(cnte, cursor);
  kscatter<<<(NE+255)/256, 256, 0, stream>>>(eg, cursor, perm, sg);
  knode<<<(NN+255)/256, 256, 0, stream>>>(nf, dp, ny, bidx, w1nT, b1n, Sn);
  kedge<<<(NE+255)/256, 256, 0, stream>>>(ef, perm, sg, w1eT, b1e, Se);
  // gh = gf + Sn@W2n + cntn*b2n + Se@W2e + cnte*b2e
  kgemm<<<dim3(8,16), 256, 0, stream>>>(Sn, w2n, gh, 0, gf, cntn, cnte, b2n, b2e,
                                        nullptr, nullptr, nullptr);
  kgemm<<<dim3(8,16), 256, 0, stream>>>(Se, w2e, gh, 1, nullptr, nullptr, nullptr, nullptr, nullptr,
                                        nullptr, nullptr, nullptr);
  // x1 = gelu(bn(gh@ow1 + ob1)), x2 = gelu(bn(x1@ow2 + ob2))
  kgemm<<<dim3(8,16), 256, 0, stream>>>(gh, ow1, x1, 2, nullptr, nullptr, nullptr, nullptr, nullptr,
                                        ob1, og1, obe1);
  kgemm<<<dim3(8,16), 256, 0, stream>>>(x1, ow2, x2, 2, nullptr, nullptr, nullptr, nullptr, nullptr,
                                        ob2, og2, obe2);
  kfinal<<<NG/4, 256, 0, stream>>>(x2, ow3, ob3, (float*)d_out);
}

// Round 2
// 581.878 us; speedup vs baseline: 1.6197x; 1.6197x over previous
//
#include <hip/hip_runtime.h>

#define NN 200000
#define NE 600000
#define NG 1024
#define HH 512

typedef short short8 __attribute__((ext_vector_type(8)));
typedef float f32x4 __attribute__((ext_vector_type(4)));

__device__ __forceinline__ unsigned short f2bf(float f){
  unsigned u = __float_as_uint(f);
  u += 0x7fffu + ((u >> 16) & 1u);
  return (unsigned short)(u >> 16);
}

// gelu(x) = x * sigmoid(1.5957691216*x + 0.07135481627*x^3)  (tanh-form GELU, |err|~5e-4)
// e^{-z} = 2^{x*(-2.3022085 - 0.10294325 x^2)}   (log2e folded into constants)
__device__ __forceinline__ float gelu_f(float x){
  float p = __builtin_fmaf(x*x, -0.10294325f, -2.3022085f);
  float e = __builtin_amdgcn_exp2f(x * p);
  return x * __builtin_amdgcn_rcpf(1.0f + e);
}

// ---------------- node segment boundaries (no atomics) ----------------
// nstart[g] = first node index with bidx >= g ; nstart[NG] = NN
__global__ void kbound(const int* __restrict__ bidx, int* __restrict__ nstart){
  int i = blockIdx.x*256 + threadIdx.x;
  if (i >= NN) return;
  int g0 = bidx[i];
  int g1 = (i+1 < NN) ? bidx[i+1] : NG;
  for (int g = g0+1; g <= g1; ++g) nstart[g] = i+1;
  if (i == 0) for (int g = 0; g <= g0; ++g) nstart[g] = 0;
}

// ---------------- edge histogram (LDS-privatized) ----------------
__global__ void khist_edge(const int* __restrict__ bidx, const int* __restrict__ eidx,
                           int* __restrict__ eg, int* __restrict__ cnte){
  __shared__ int h[NG];
  for (int t = threadIdx.x; t < NG; t += 256) h[t] = 0;
  __syncthreads();
  for (int e = blockIdx.x*256 + threadIdx.x; e < NE; e += gridDim.x*256){
    int g = bidx[eidx[e]];
    eg[e] = g;
    atomicAdd(&h[g], 1);
  }
  __syncthreads();
  for (int t = threadIdx.x; t < NG; t += 256){ int c = h[t]; if (c) atomicAdd(&cnte[t], c); }
}

__global__ void kscan(const int* __restrict__ cnte, int* __restrict__ cursor){
  __shared__ int s[NG];
  int t = threadIdx.x;
  int v = cnte[t]; s[t] = v; __syncthreads();
  for (int d = 1; d < NG; d <<= 1){
    int x = (t >= d) ? s[t-d] : 0;
    __syncthreads();
    s[t] += x;
    __syncthreads();
  }
  cursor[t] = s[t] - v;   // exclusive prefix
}

// ---------------- scatter with per-block LDS ranking (few global atomics) ----------------
__global__ __launch_bounds__(1024) void kscatter(const int* __restrict__ eg, int* __restrict__ cursor,
                                                 int* __restrict__ perm, int* __restrict__ sg){
  __shared__ int h[NG], base[NG];
  const int per = (NE + gridDim.x - 1) / gridDim.x;
  const int lo = blockIdx.x * per, hi = min(lo + per, NE);
  for (int t = threadIdx.x; t < NG; t += 1024) h[t] = 0;
  __syncthreads();
  for (int e = lo + threadIdx.x; e < hi; e += 1024) atomicAdd(&h[eg[e]], 1);
  __syncthreads();
  for (int t = threadIdx.x; t < NG; t += 1024){
    int c = h[t];
    base[t] = c ? atomicAdd(&cursor[t], c) : 0;
    h[t] = 0;
  }
  __syncthreads();
  for (int e = lo + threadIdx.x; e < hi; e += 1024){
    int g = eg[e];
    int p = base[g] + atomicAdd(&h[g], 1);
    perm[p] = e; sg[p] = g;
  }
}

// ---------------- weight prep: fold BN scale into W1/b1, bf16 B^T layout ----------------
__global__ void kprep(const float* __restrict__ nfw1, const float* __restrict__ nfb1,
                      const float* __restrict__ nfg1, const float* __restrict__ nfbe1,
                      const float* __restrict__ efw1, const float* __restrict__ efb1,
                      const float* __restrict__ efg1, const float* __restrict__ efbe1,
                      unsigned short* __restrict__ w1nT, unsigned short* __restrict__ w1eT,
                      float* __restrict__ b1n, float* __restrict__ b1e){
  const float rs = 0.99999500003750f;   // 1/sqrt(1+1e-5)
  int tid = blockIdx.x*256 + threadIdx.x;
  if (tid < 512*64){
    int c = tid >> 6, k = tid & 63;
    float w = (k < 41) ? nfw1[k*HH + c] * nfg1[c] * rs : 0.0f;
    w1nT[tid] = f2bf(w);
  } else if (tid < 512*96){
    int u = tid - 512*64; int c = u >> 5, k = u & 31;
    float w = (k < 16) ? efw1[k*HH + c] * efg1[c] * rs : 0.0f;
    w1eT[u] = f2bf(w);
  } else if (tid < 512*96 + 512){
    int c = tid - 512*96;
    b1n[c] = nfb1[c]*nfg1[c]*rs + nfbe1[c];
  } else if (tid < 512*96 + 1024){
    int c = tid - (512*96 + 512);
    b1e[c] = efb1[c]*efg1[c]*rs + efbe1[c];
  }
}

// ---------------- node first layer: MFMA + gelu + hierarchical segment-sum ----------------
__global__ __launch_bounds__(256) void knode(const float* __restrict__ nf, const float* __restrict__ dp,
    const int* __restrict__ ny, const int* __restrict__ bidx,
    const unsigned short* __restrict__ w1nT, const float* __restrict__ b1n, float* __restrict__ S){
  __shared__ float sred[4*512];
  const int lane = threadIdx.x & 63, wv = threadIdx.x >> 6;
  const int q = lane >> 4, m = lane & 15;
  const int blk0 = blockIdx.x*256;
  const int r0 = blk0 + wv*64;
  bool bok = (blk0 + 255 < NN) && (bidx[blk0] == bidx[blk0+255]);
  int gBlk = bidx[min(blk0, NN-1)];
  short8 a0[4], a1[4];
  int4 g4[4];
  int gfi[4], gla[4]; bool tok[4];
  const short8 zz = {0,0,0,0,0,0,0,0};
#pragma unroll
  for (int rt=0; rt<4; ++rt){
    int rb = r0 + rt*16;
    int row = rb + m;
    bool valid = row < NN;
    int ar = valid ? row : (NN-1);
    const float4* ap = (const float4*)(nf + (size_t)ar*32 + q*8);
    float4 xa = ap[0], xb = ap[1];
    short8 f;
    f[0]=(short)f2bf(xa.x); f[1]=(short)f2bf(xa.y); f[2]=(short)f2bf(xa.z); f[3]=(short)f2bf(xa.w);
    f[4]=(short)f2bf(xb.x); f[5]=(short)f2bf(xb.y); f[6]=(short)f2bf(xb.z); f[7]=(short)f2bf(xb.w);
    if (!valid) f = zz;
    a0[rt] = f;
    int cls = ny[ar];
    short dpb = (short)f2bf(dp[ar]);
    short8 h = zz;
    if (valid){
      if (q == 0){
#pragma unroll
        for (int j=0;j<8;++j) h[j] = (cls==j) ? dpb : (short)0;
      } else if (q == 1 && cls == 8) h[0] = dpb;
    }
    a1[rt] = h;
    int gb = rb + q*4;
    if (gb + 3 < NN) g4[rt] = *(const int4*)(bidx + gb);
    else {
      g4[rt].x = (gb   < NN) ? bidx[gb  ] : -1;
      g4[rt].y = (gb+1 < NN) ? bidx[gb+1] : -1;
      g4[rt].z = (gb+2 < NN) ? bidx[gb+2] : -1;
      g4[rt].w = (gb+3 < NN) ? bidx[gb+3] : -1;
    }
    int gA = bidx[min(rb, NN-1)], gB = bidx[min(rb+15, NN-1)];
    tok[rt] = (rb + 15 < NN) && (gA == gB);
    gfi[rt] = gA; gla[rt] = gB;
  }
  int gW = bidx[min(r0, NN-1)];
  bool wok = (r0 + 63 < NN) && (gW == bidx[min(r0+63, NN-1)]);

  for (int nt=0; nt<32; ++nt){
    const short8* bp = (const short8*)(w1nT + ((nt*16 + m) << 6) + (q << 3));
    short8 b0 = bp[0];
    short8 b1 = bp[4];
    float bias = b1n[(nt<<4) + m];
    float wsum = 0.0f;
#pragma unroll
    for (int rt=0; rt<4; ++rt){
      f32x4 acc = {0.f,0.f,0.f,0.f};
      acc = __builtin_amdgcn_mfma_f32_16x16x32_bf16(a0[rt], b0, acc, 0, 0, 0);
      acc = __builtin_amdgcn_mfma_f32_16x16x32_bf16(a1[rt], b1, acc, 0, 0, 0);
      float v0 = gelu_f(acc[0] + bias);
      float v1 = gelu_f(acc[1] + bias);
      float v2 = gelu_f(acc[2] + bias);
      float v3 = gelu_f(acc[3] + bias);
      if (wok){
        wsum += (v0+v1)+(v2+v3);
      } else if (tok[rt]){
        float ts = (v0+v1)+(v2+v3);
        ts += __shfl_xor(ts, 16);
        ts += __shfl_xor(ts, 32);
        if (lane < 16) unsafeAtomicAdd(&S[(size_t)gfi[rt]*1024 + (nt<<4) + lane], ts);
      } else {
        // boundary tile: masked two-graph reduction
        int gA = gfi[rt], gB = gla[rt];
        float sA = 0.f, sB = 0.f;
        sA += (g4[rt].x==gA)?v0:0.f; sB += (g4[rt].x==gB)?v0:0.f;
        sA += (g4[rt].y==gA)?v1:0.f; sB += (g4[rt].y==gB)?v1:0.f;
        sA += (g4[rt].z==gA)?v2:0.f; sB += (g4[rt].z==gB)?v2:0.f;
        sA += (g4[rt].w==gA)?v3:0.f; sB += (g4[rt].w==gB)?v3:0.f;
        int cb = (nt<<4) + m;
        if (g4[rt].x>=0 && g4[rt].x!=gA && g4[rt].x!=gB) unsafeAtomicAdd(&S[(size_t)g4[rt].x*1024 + cb], v0);
        if (g4[rt].y>=0 && g4[rt].y!=gA && g4[rt].y!=gB) unsafeAtomicAdd(&S[(size_t)g4[rt].y*1024 + cb], v1);
        if (g4[rt].z>=0 && g4[rt].z!=gA && g4[rt].z!=gB) unsafeAtomicAdd(&S[(size_t)g4[rt].z*1024 + cb], v2);
        if (g4[rt].w>=0 && g4[rt].w!=gA && g4[rt].w!=gB) unsafeAtomicAdd(&S[(size_t)g4[rt].w*1024 + cb], v3);
        sA += __shfl_xor(sA, 16); sA += __shfl_xor(sA, 32);
        sB += __shfl_xor(sB, 16); sB += __shfl_xor(sB, 32);
        if (lane < 16){
          unsafeAtomicAdd(&S[(size_t)gA*1024 + (nt<<4) + lane], sA);
          unsafeAtomicAdd(&S[(size_t)gB*1024 + (nt<<4) + lane], sB);
        }
      }
    }
    if (wok){
      wsum += __shfl_xor(wsum, 16);
      wsum += __shfl_xor(wsum, 32);
      if (bok){
        if (lane < 16) sred[wv*512 + (nt<<4) + lane] = wsum;
      } else if (lane < 16){
        unsafeAtomicAdd(&S[(size_t)gW*1024 + (nt<<4) + lane], wsum);
      }
    }
  }
  if (bok){
    __syncthreads();
    int t = threadIdx.x;
#pragma unroll
    for (int hh=0; hh<2; ++hh){
      int col = t + hh*256;
      float s = (sred[col] + sred[512+col]) + (sred[1024+col] + sred[1536+col]);
      unsafeAtomicAdd(&S[(size_t)gBlk*1024 + col], s);
    }
  }
}

// ---------------- edge first layer (sorted by graph via perm/sg) ----------------
__global__ __launch_bounds__(256) void kedge(const float* __restrict__ ef, const int* __restrict__ perm,
    const int* __restrict__ sg, const unsigned short* __restrict__ w1eT, const float* __restrict__ b1e,
    float* __restrict__ S){
  __shared__ float sred[4*512];
  const int lane = threadIdx.x & 63, wv = threadIdx.x >> 6;
  const int q = lane >> 4, m = lane & 15;
  const int blk0 = blockIdx.x*256;
  const int r0 = blk0 + wv*64;
  bool bok = (blk0 + 255 < NE) && (sg[blk0] == sg[blk0+255]);
  int gBlk = sg[min(blk0, NE-1)];
  short8 a0[4];
  int4 g4[4];
  int gfi[4], gla[4]; bool tok[4];
  const short8 zz = {0,0,0,0,0,0,0,0};
#pragma unroll
  for (int rt=0; rt<4; ++rt){
    int rb = r0 + rt*16;
    int row = rb + m;
    bool valid = row < NE;
    int e = perm[valid ? row : (NE-1)];
    short8 f = zz;
    if (valid && q < 2){
      const float4* ap = (const float4*)(ef + (size_t)e*16 + q*8);
      float4 xa = ap[0], xb = ap[1];
      f[0]=(short)f2bf(xa.x); f[1]=(short)f2bf(xa.y); f[2]=(short)f2bf(xa.z); f[3]=(short)f2bf(xa.w);
      f[4]=(short)f2bf(xb.x); f[5]=(short)f2bf(xb.y); f[6]=(short)f2bf(xb.z); f[7]=(short)f2bf(xb.w);
    }
    a0[rt] = f;
    int gb = rb + q*4;
    if (gb + 3 < NE) g4[rt] = *(const int4*)(sg + gb);
    else {
      g4[rt].x = (gb   < NE) ? sg[gb  ] : -1;
      g4[rt].y = (gb+1 < NE) ? sg[gb+1] : -1;
      g4[rt].z = (gb+2 < NE) ? sg[gb+2] : -1;
      g4[rt].w = (gb+3 < NE) ? sg[gb+3] : -1;
    }
    int gA = sg[min(rb, NE-1)], gB = sg[min(rb+15, NE-1)];
    tok[rt] = (rb + 15 < NE) && (gA == gB);
    gfi[rt] = gA; gla[rt] = gB;
  }
  int gW = sg[min(r0, NE-1)];
  bool wok = (r0 + 63 < NE) && (gW == sg[min(r0+63, NE-1)]);

  for (int nt=0; nt<32; ++nt){
    short8 b0 = *(const short8*)(w1eT + ((nt*16 + m) << 5) + (q << 3));
    float bias = b1e[(nt<<4) + m];
    float wsum = 0.0f;
#pragma unroll
    for (int rt=0; rt<4; ++rt){
      f32x4 acc = {0.f,0.f,0.f,0.f};
      acc = __builtin_amdgcn_mfma_f32_16x16x32_bf16(a0[rt], b0, acc, 0, 0, 0);
      float v0 = gelu_f(acc[0] + bias);
      float v1 = gelu_f(acc[1] + bias);
      float v2 = gelu_f(acc[2] + bias);
      float v3 = gelu_f(acc[3] + bias);
      if (wok){
        wsum += (v0+v1)+(v2+v3);
      } else if (tok[rt]){
        float ts = (v0+v1)+(v2+v3);
        ts += __shfl_xor(ts, 16);
        ts += __shfl_xor(ts, 32);
        if (lane < 16) unsafeAtomicAdd(&S[(size_t)gfi[rt]*1024 + 512 + (nt<<4) + lane], ts);
      } else {
        int gA = gfi[rt], gB = gla[rt];
        float sA = 0.f, sB = 0.f;
        sA += (g4[rt].x==gA)?v0:0.f; sB += (g4[rt].x==gB)?v0:0.f;
        sA += (g4[rt].y==gA)?v1:0.f; sB += (g4[rt].y==gB)?v1:0.f;
        sA += (g4[rt].z==gA)?v2:0.f; sB += (g4[rt].z==gB)?v2:0.f;
        sA += (g4[rt].w==gA)?v3:0.f; sB += (g4[rt].w==gB)?v3:0.f;
        int cb = (nt<<4) + m;
        if (g4[rt].x>=0 && g4[rt].x!=gA && g4[rt].x!=gB) unsafeAtomicAdd(&S[(size_t)g4[rt].x*1024 + 512 + cb], v0);
        if (g4[rt].y>=0 && g4[rt].y!=gA && g4[rt].y!=gB) unsafeAtomicAdd(&S[(size_t)g4[rt].y*1024 + 512 + cb], v1);
        if (g4[rt].z>=0 && g4[rt].z!=gA && g4[rt].z!=gB) unsafeAtomicAdd(&S[(size_t)g4[rt].z*1024 + 512 + cb], v2);
        if (g4[rt].w>=0 && g4[rt].w!=gA && g4[rt].w!=gB) unsafeAtomicAdd(&S[(size_t)g4[rt].w*1024 + 512 + cb], v3);
        sA += __shfl_xor(sA, 16); sA += __shfl_xor(sA, 32);
        sB += __shfl_xor(sB, 16); sB += __shfl_xor(sB, 32);
        if (lane < 16){
          unsafeAtomicAdd(&S[(size_t)gA*1024 + 512 + (nt<<4) + lane], sA);
          unsafeAtomicAdd(&S[(size_t)gB*1024 + 512 + (nt<<4) + lane], sB);
        }
      }
    }
    if (wok){
      wsum += __shfl_xor(wsum, 16);
      wsum += __shfl_xor(wsum, 32);
      if (bok){
        if (lane < 16) sred[wv*512 + (nt<<4) + lane] = wsum;
      } else if (lane < 16){
        unsafeAtomicAdd(&S[(size_t)gW*1024 + 512 + (nt<<4) + lane], wsum);
      }
    }
  }
  if (bok){
    __syncthreads();
    int t = threadIdx.x;
#pragma unroll
    for (int hh=0; hh<2; ++hh){
      int col = t + hh*256;
      float s = (sred[col] + sred[512+col]) + (sred[1024+col] + sred[1536+col]);
      unsafeAtomicAdd(&S[(size_t)gBlk*1024 + 512 + col], s);
    }
  }
}

// ---------------- finish GEMMs, fp32, fused epilogues ----------------
// mode 0: out = A@[B0;B1] + gf + cntn*b2n + cnte*b2e   (A is 1024 x (nkt*16), lda)
// mode 2: out = gelu((A@B0 + bias)*gam*rs + bet)
__global__ __launch_bounds__(256) void kgemm(const float* __restrict__ A, int lda, int nkt,
    const float* __restrict__ B0, const float* __restrict__ B1, float* __restrict__ out,
    int mode, const float* __restrict__ gf, const int* __restrict__ nstart,
    const int* __restrict__ cnte, const float* __restrict__ b2n, const float* __restrict__ b2e,
    const float* __restrict__ bias, const float* __restrict__ gam, const float* __restrict__ bet){
  __shared__ float Ast[16*68];
  __shared__ float Bs[16*68];
  const int t = threadIdx.x, tx = t & 15, ty = t >> 4;
  const int c0 = blockIdx.x*64, r0 = blockIdx.y*64;
  float acc[4][4] = {};
  for (int ks=0; ks<nkt; ++ks){
    const int k0 = ks*16;
    const float* Bp = (k0 < HH) ? (B0 + (size_t)k0*HH) : (B1 + (size_t)(k0-HH)*HH);
#pragma unroll
    for (int u=0; u<4; ++u){
      int ff = t + u*256;
      Ast[(ff & 15)*68 + (ff >> 4)] = A[(size_t)(r0 + (ff >> 4))*lda + k0 + (ff & 15)];
      Bs[(ff >> 6)*68 + (ff & 63)] = Bp[(size_t)(ff >> 6)*HH + c0 + (ff & 63)];
    }
    __syncthreads();
#pragma unroll
    for (int k=0;k<16;++k){
      float4 a4 = *(const float4*)&Ast[k*68 + ty*4];
      float4 b4 = *(const float4*)&Bs[k*68 + tx*4];
      float av[4] = {a4.x, a4.y, a4.z, a4.w};
      float bv[4] = {b4.x, b4.y, b4.z, b4.w};
#pragma unroll
      for (int i=0;i<4;++i)
#pragma unroll
        for (int j=0;j<4;++j) acc[i][j] = __builtin_fmaf(av[i], bv[j], acc[i][j]);
    }
    __syncthreads();
  }
  const int r = r0 + ty*4, c = c0 + tx*4;
  if (mode == 0){
    float4 bn4 = *(const float4*)&b2n[c];
    float4 be4 = *(const float4*)&b2e[c];
#pragma unroll
    for (int i=0;i<4;++i){
      float4 gv = *(const float4*)&gf[(size_t)(r+i)*HH + c];
      float cn = (float)(nstart[r+i+1] - nstart[r+i]);
      float ce = (float)cnte[r+i];
      float4 o;
      o.x = acc[i][0] + gv.x + cn*bn4.x + ce*be4.x;
      o.y = acc[i][1] + gv.y + cn*bn4.y + ce*be4.y;
      o.z = acc[i][2] + gv.z + cn*bn4.z + ce*be4.z;
      o.w = acc[i][3] + gv.w + cn*bn4.w + ce*be4.w;
      *(float4*)&out[(size_t)(r+i)*HH + c] = o;
    }
  } else {
    const float rs = 0.99999500003750f;
    float4 ga = *(const float4*)&gam[c];
    float4 bi = *(const float4*)&bias[c];
    float4 be = *(const float4*)&bet[c];
    float s0 = ga.x*rs, s1 = ga.y*rs, s2 = ga.z*rs, s3 = ga.w*rs;
#pragma unroll
    for (int i=0;i<4;++i){
      float4 o;
      o.x = gelu_f((acc[i][0] + bi.x)*s0 + be.x);
      o.y = gelu_f((acc[i][1] + bi.y)*s1 + be.y);
      o.z = gelu_f((acc[i][2] + bi.z)*s2 + be.z);
      o.w = gelu_f((acc[i][3] + bi.w)*s3 + be.w);
      *(float4*)&out[(size_t)(r+i)*HH + c] = o;
    }
  }
}

// ---------------- final 512 -> 2 linear ----------------
__global__ __launch_bounds__(256) void kfinal(const float* __restrict__ x2, const float* __restrict__ w3,
    const float* __restrict__ b3, float* __restrict__ out){
  const int lane = threadIdx.x & 63, wv = threadIdx.x >> 6;
  const int r = blockIdx.x*4 + wv;
  float a0 = 0.f, a1 = 0.f;
#pragma unroll
  for (int tt=0; tt<8; ++tt){
    int k = lane + tt*64;
    float x = x2[(size_t)r*HH + k];
    a0 = __builtin_fmaf(x, w3[2*k], a0);
    a1 = __builtin_fmaf(x, w3[2*k+1], a1);
  }
#pragma unroll
  for (int d=1; d<64; d<<=1){ a0 += __shfl_xor(a0, d); a1 += __shfl_xor(a1, d); }
  if (lane == 0){ out[r*2] = a0 + b3[0]; out[r*2+1] = a1 + b3[1]; }
}

extern "C" void kernel_launch(void* const* d_in, const int* in_sizes, int n_in,
                              void* d_out, int out_size, void* d_ws, size_t ws_size,
                              hipStream_t stream) {
  const float* nf    = (const float*)d_in[0];
  const float* ef    = (const float*)d_in[1];
  const float* gf    = (const float*)d_in[2];
  const float* dp    = (const float*)d_in[3];
  const int*   ny    = (const int*)d_in[4];
  const int*   bidx  = (const int*)d_in[5];
  const int*   eidx  = (const int*)d_in[6];
  const float* nfw1  = (const float*)d_in[7];
  const float* nfb1  = (const float*)d_in[8];
  const float* nfg1  = (const float*)d_in[9];
  const float* nfbe1 = (const float*)d_in[10];
  const float* w2n   = (const float*)d_in[11];
  const float* b2n   = (const float*)d_in[12];
  const float* efw1  = (const float*)d_in[13];
  const float* efb1  = (const float*)d_in[14];
  const float* efg1  = (const float*)d_in[15];
  const float* efbe1 = (const float*)d_in[16];
  const float* w2e   = (const float*)d_in[17];
  const float* b2e   = (const float*)d_in[18];
  const float* ow1   = (const float*)d_in[19];
  const float* ob1   = (const float*)d_in[20];
  const float* og1   = (const float*)d_in[21];
  const float* obe1  = (const float*)d_in[22];
  const float* ow2   = (const float*)d_in[23];
  const float* ob2   = (const float*)d_in[24];
  const float* og2   = (const float*)d_in[25];
  const float* obe2  = (const float*)d_in[26];
  const float* ow3   = (const float*)d_in[27];
  const float* ob3   = (const float*)d_in[28];

  // workspace carve (S first so one memset covers S+cnte+cursor)
  float* S    = (float*)d_ws;                 // 1024 x 1024 (node cols 0-511, edge cols 512-1023)
  int* cnte   = (int*)(S + NG*1024);          // 1024
  int* cursor = cnte + NG;                    // 1024
  int* nstart = cursor + NG;                  // 1025
  int* eg     = nstart + NG + 1;              // NE
  int* perm   = eg + NE;                      // NE
  int* sg     = perm + NE;                    // NE
  unsigned short* w1nT = (unsigned short*)(sg + NE);  // 512*64
  unsigned short* w1eT = w1nT + HH*64;                // 512*32
  float* b1n  = (float*)(w1eT + HH*32);       // 512
  float* b1e  = b1n + HH;                     // 512
  float* gh   = b1e + HH;                     // 1024*512
  float* x1   = gh + NG*HH;                   // 1024*512
  float* x2   = x1 + NG*HH;                   // 1024*512

  hipMemsetAsync(d_ws, 0, (size_t)NG*1024*sizeof(float) + 2*NG*sizeof(int), stream);

  kprep<<<196, 256, 0, stream>>>(nfw1, nfb1, nfg1, nfbe1, efw1, efb1, efg1, efbe1,
                                 w1nT, w1eT, b1n, b1e);
  kbound<<<(NN+255)/256, 256, 0, stream>>>(bidx, nstart);
  khist_edge<<<256, 256, 0, stream>>>(bidx, eidx, eg, cnte);
  kscan<<<1, NG, 0, stream>>>(cnte, cursor);
  kscatter<<<128, 1024, 0, stream>>>(eg, cursor, perm, sg);
  knode<<<(NN+255)/256, 256, 0, stream>>>(nf, dp, ny, bidx, w1nT, b1n, S);
  kedge<<<(NE+255)/256, 256, 0, stream>>>(ef, perm, sg, w1eT, b1e, S);
  // gh = gf + [Sn|Se] @ [W2n;W2e] + cntn*b2n + cnte*b2e
  kgemm<<<dim3(8,16), 256, 0, stream>>>(S, 1024, 64, w2n, w2e, gh, 0, gf, nstart, cnte, b2n, b2e,
                                        nullptr, nullptr, nullptr);
  kgemm<<<dim3(8,16), 256, 0, stream>>>(gh, 512, 32, ow1, ow1, x1, 2, nullptr, nullptr, nullptr,
                                        nullptr, nullptr, ob1, og1, obe1);
  kgemm<<<dim3(8,16), 256, 0, stream>>>(x1, 512, 32, ow2, ow2, x2, 2, nullptr, nullptr, nullptr,
                                        nullptr, nullptr, ob2, og2, obe2);
  kfinal<<<NG/4, 256, 0, stream>>>(x2, ow3, ob3, (float*)d_out);
}

// Round 3
// 552.418 us; speedup vs baseline: 1.7061x; 1.0533x over previous
//
#include <hip/hip_runtime.h>

#define NN 200000
#define NE 600000
#define NG 1024
#define HH 512

typedef short short8 __attribute__((ext_vector_type(8)));
typedef float f32x4 __attribute__((ext_vector_type(4)));

__device__ __forceinline__ unsigned short f2bf(float f){
  unsigned u = __float_as_uint(f);
  u += 0x7fffu + ((u >> 16) & 1u);
  return (unsigned short)(u >> 16);
}

// gelu(x) = x * sigmoid(1.5957691216*x + 0.07135481627*x^3)  (tanh-form GELU, |err|~5e-4)
// e^{-z} computed as 2^{x*(-2.3022085 - 0.10294325 x^2)}
__device__ __forceinline__ float gelu_f(float x){
  float p = __builtin_fmaf(x*x, -0.10294325f, -2.3022085f);
  float e = __builtin_amdgcn_exp2f(x * p);
  return x * __builtin_amdgcn_rcpf(1.0f + e);
}

// ---------------- node segment boundaries (no atomics) ----------------
__global__ void kbound(const int* __restrict__ bidx, int* __restrict__ nstart){
  int i = blockIdx.x*256 + threadIdx.x;
  if (i >= NN) return;
  int g0 = bidx[i];
  int g1 = (i+1 < NN) ? bidx[i+1] : NG;
  for (int g = g0+1; g <= g1; ++g) nstart[g] = i+1;
  if (i == 0) for (int g = 0; g <= g0; ++g) nstart[g] = 0;
}

// ---------------- edge histogram (LDS-privatized) ----------------
__global__ void khist_edge(const int* __restrict__ bidx, const int* __restrict__ eidx,
                           int* __restrict__ eg, int* __restrict__ cnte){
  __shared__ int h[NG];
  for (int t = threadIdx.x; t < NG; t += 256) h[t] = 0;
  __syncthreads();
  for (int e = blockIdx.x*256 + threadIdx.x; e < NE; e += gridDim.x*256){
    int g = bidx[eidx[e]];
    eg[e] = g;
    atomicAdd(&h[g], 1);
  }
  __syncthreads();
  for (int t = threadIdx.x; t < NG; t += 256){ int c = h[t]; if (c) atomicAdd(&cnte[t], c); }
}

__global__ void kscan(const int* __restrict__ cnte, int* __restrict__ cursor){
  __shared__ int s[NG];
  int t = threadIdx.x;
  int v = cnte[t]; s[t] = v; __syncthreads();
  for (int d = 1; d < NG; d <<= 1){
    int x = (t >= d) ? s[t-d] : 0;
    __syncthreads();
    s[t] += x;
    __syncthreads();
  }
  cursor[t] = s[t] - v;
}

__global__ __launch_bounds__(1024) void kscatter(const int* __restrict__ eg, int* __restrict__ cursor,
                                                 int* __restrict__ perm, int* __restrict__ sg){
  __shared__ int h[NG], base[NG];
  const int per = (NE + gridDim.x - 1) / gridDim.x;
  const int lo = blockIdx.x * per, hi = min(lo + per, NE);
  for (int t = threadIdx.x; t < NG; t += 1024) h[t] = 0;
  __syncthreads();
  for (int e = lo + threadIdx.x; e < hi; e += 1024) atomicAdd(&h[eg[e]], 1);
  __syncthreads();
  for (int t = threadIdx.x; t < NG; t += 1024){
    int c = h[t];
    base[t] = c ? atomicAdd(&cursor[t], c) : 0;
    h[t] = 0;
  }
  __syncthreads();
  for (int e = lo + threadIdx.x; e < hi; e += 1024){
    int g = eg[e];
    int p = base[g] + atomicAdd(&h[g], 1);
    perm[p] = e; sg[p] = g;
  }
}

// ---------------- weight prep ----------------
__global__ void kprep(const float* __restrict__ nfw1, const float* __restrict__ nfb1,
                      const float* __restrict__ nfg1, const float* __restrict__ nfbe1,
                      const float* __restrict__ efw1, const float* __restrict__ efb1,
                      const float* __restrict__ efg1, const float* __restrict__ efbe1,
                      unsigned short* __restrict__ w1nT, unsigned short* __restrict__ w1eT,
                      float* __restrict__ b1n, float* __restrict__ b1e){
  const float rs = 0.99999500003750f;
  int tid = blockIdx.x*256 + threadIdx.x;
  if (tid < 512*64){
    int c = tid >> 6, k = tid & 63;
    float w = (k < 41) ? nfw1[k*HH + c] * nfg1[c] * rs : 0.0f;
    w1nT[tid] = f2bf(w);
  } else if (tid < 512*96){
    int u = tid - 512*64; int c = u >> 5, k = u & 31;
    float w = (k < 16) ? efw1[k*HH + c] * efg1[c] * rs : 0.0f;
    w1eT[u] = f2bf(w);
  } else if (tid < 512*96 + 512){
    int c = tid - 512*96;
    b1n[c] = nfb1[c]*nfg1[c]*rs + nfbe1[c];
  } else if (tid < 512*96 + 1024){
    int c = tid - (512*96 + 512);
    b1e[c] = efb1[c]*efg1[c]*rs + efbe1[c];
  }
}

// ---------------- node first layer: MFMA + gelu + segment-sum (rt=2, prefetch) ----------------
__global__ __launch_bounds__(256) void knode(const float* __restrict__ nf, const float* __restrict__ dp,
    const int* __restrict__ ny, const int* __restrict__ bidx,
    const unsigned short* __restrict__ w1nT, const float* __restrict__ b1n, float* __restrict__ S){
  const int lane = threadIdx.x & 63, wv = threadIdx.x >> 6;
  const int q = lane >> 4, m = lane & 15;
  const int r0 = blockIdx.x*128 + wv*32;
  short8 a0[2], a1[2];
  int4 g4[2];
  int gfi[2], gla[2]; bool tok[2];
  const short8 zz = {0,0,0,0,0,0,0,0};
#pragma unroll
  for (int rt=0; rt<2; ++rt){
    int rb = r0 + rt*16;
    int row = rb + m;
    bool valid = row < NN;
    int ar = valid ? row : (NN-1);
    const float4* ap = (const float4*)(nf + (size_t)ar*32 + q*8);
    float4 xa = ap[0], xb = ap[1];
    short8 f;
    f[0]=(short)f2bf(xa.x); f[1]=(short)f2bf(xa.y); f[2]=(short)f2bf(xa.z); f[3]=(short)f2bf(xa.w);
    f[4]=(short)f2bf(xb.x); f[5]=(short)f2bf(xb.y); f[6]=(short)f2bf(xb.z); f[7]=(short)f2bf(xb.w);
    if (!valid) f = zz;
    a0[rt] = f;
    int cls = ny[ar];
    short dpb = (short)f2bf(dp[ar]);
    short8 h = zz;
    if (valid){
      if (q == 0){
#pragma unroll
        for (int j=0;j<8;++j) h[j] = (cls==j) ? dpb : (short)0;
      } else if (q == 1 && cls == 8) h[0] = dpb;
    }
    a1[rt] = h;
    int gb = rb + q*4;
    if (gb + 3 < NN) g4[rt] = *(const int4*)(bidx + gb);
    else {
      g4[rt].x = (gb   < NN) ? bidx[gb  ] : -1;
      g4[rt].y = (gb+1 < NN) ? bidx[gb+1] : -1;
      g4[rt].z = (gb+2 < NN) ? bidx[gb+2] : -1;
      g4[rt].w = (gb+3 < NN) ? bidx[gb+3] : -1;
    }
    int gA = bidx[min(rb, NN-1)], gB = bidx[min(rb+15, NN-1)];
    tok[rt] = (rb + 15 < NN) && (gA == gB);
    gfi[rt] = gA; gla[rt] = gB;
  }
  int gW = bidx[min(r0, NN-1)];
  bool wok = (r0 + 31 < NN) && (gW == bidx[min(r0+31, NN-1)]);

  // prefetch nt=0 B-fragments + bias
  const short8* bp0 = (const short8*)(w1nT + (m << 6) + (q << 3));
  short8 b0 = bp0[0], b1 = bp0[4];
  float bias = b1n[m];

  for (int nt=0; nt<32; ++nt){
    int ntn = (nt + 1) & 31;
    const short8* np = (const short8*)(w1nT + (((ntn<<4) + m) << 6) + (q << 3));
    short8 pb0 = np[0], pb1 = np[4];
    float pbias = b1n[(ntn<<4) + m];
    float wsum = 0.0f;
#pragma unroll
    for (int rt=0; rt<2; ++rt){
      f32x4 acc = {bias, bias, bias, bias};
      acc = __builtin_amdgcn_mfma_f32_16x16x32_bf16(a0[rt], b0, acc, 0, 0, 0);
      acc = __builtin_amdgcn_mfma_f32_16x16x32_bf16(a1[rt], b1, acc, 0, 0, 0);
      float v0 = gelu_f(acc[0]);
      float v1 = gelu_f(acc[1]);
      float v2 = gelu_f(acc[2]);
      float v3 = gelu_f(acc[3]);
      if (wok){
        wsum += (v0+v1)+(v2+v3);
      } else if (tok[rt]){
        float ts = (v0+v1)+(v2+v3);
        ts += __shfl_xor(ts, 16);
        ts += __shfl_xor(ts, 32);
        if (lane < 16) unsafeAtomicAdd(&S[(size_t)gfi[rt]*1024 + (nt<<4) + lane], ts);
      } else {
        int gA = gfi[rt], gB = gla[rt];
        float sA = 0.f, sB = 0.f;
        sA += (g4[rt].x==gA)?v0:0.f; sB += (g4[rt].x==gB)?v0:0.f;
        sA += (g4[rt].y==gA)?v1:0.f; sB += (g4[rt].y==gB)?v1:0.f;
        sA += (g4[rt].z==gA)?v2:0.f; sB += (g4[rt].z==gB)?v2:0.f;
        sA += (g4[rt].w==gA)?v3:0.f; sB += (g4[rt].w==gB)?v3:0.f;
        int cb = (nt<<4) + m;
        if (g4[rt].x>=0 && g4[rt].x!=gA && g4[rt].x!=gB) unsafeAtomicAdd(&S[(size_t)g4[rt].x*1024 + cb], v0);
        if (g4[rt].y>=0 && g4[rt].y!=gA && g4[rt].y!=gB) unsafeAtomicAdd(&S[(size_t)g4[rt].y*1024 + cb], v1);
        if (g4[rt].z>=0 && g4[rt].z!=gA && g4[rt].z!=gB) unsafeAtomicAdd(&S[(size_t)g4[rt].z*1024 + cb], v2);
        if (g4[rt].w>=0 && g4[rt].w!=gA && g4[rt].w!=gB) unsafeAtomicAdd(&S[(size_t)g4[rt].w*1024 + cb], v3);
        sA += __shfl_xor(sA, 16); sA += __shfl_xor(sA, 32);
        sB += __shfl_xor(sB, 16); sB += __shfl_xor(sB, 32);
        if (lane < 16){
          unsafeAtomicAdd(&S[(size_t)gA*1024 + (nt<<4) + lane], sA);
          unsafeAtomicAdd(&S[(size_t)gB*1024 + (nt<<4) + lane], sB);
        }
      }
    }
    if (wok){
      wsum += __shfl_xor(wsum, 16);
      wsum += __shfl_xor(wsum, 32);
      if (lane < 16) unsafeAtomicAdd(&S[(size_t)gW*1024 + (nt<<4) + lane], wsum);
    }
    b0 = pb0; b1 = pb1; bias = pbias;
  }
}

// ---------------- edge first layer (sorted via perm/sg; rt=2, prefetch) ----------------
__global__ __launch_bounds__(256) void kedge(const float* __restrict__ ef, const int* __restrict__ perm,
    const int* __restrict__ sg, const unsigned short* __restrict__ w1eT, const float* __restrict__ b1e,
    float* __restrict__ S){
  const int lane = threadIdx.x & 63, wv = threadIdx.x >> 6;
  const int q = lane >> 4, m = lane & 15;
  const int r0 = blockIdx.x*128 + wv*32;
  short8 a0[2];
  int4 g4[2];
  int gfi[2], gla[2]; bool tok[2];
  const short8 zz = {0,0,0,0,0,0,0,0};
#pragma unroll
  for (int rt=0; rt<2; ++rt){
    int rb = r0 + rt*16;
    int row = rb + m;
    bool valid = row < NE;
    int e = perm[valid ? row : (NE-1)];
    short8 f = zz;
    if (valid && q < 2){
      const float4* ap = (const float4*)(ef + (size_t)e*16 + q*8);
      float4 xa = ap[0], xb = ap[1];
      f[0]=(short)f2bf(xa.x); f[1]=(short)f2bf(xa.y); f[2]=(short)f2bf(xa.z); f[3]=(short)f2bf(xa.w);
      f[4]=(short)f2bf(xb.x); f[5]=(short)f2bf(xb.y); f[6]=(short)f2bf(xb.z); f[7]=(short)f2bf(xb.w);
    }
    a0[rt] = f;
    int gb = rb + q*4;
    if (gb + 3 < NE) g4[rt] = *(const int4*)(sg + gb);
    else {
      g4[rt].x = (gb   < NE) ? sg[gb  ] : -1;
      g4[rt].y = (gb+1 < NE) ? sg[gb+1] : -1;
      g4[rt].z = (gb+2 < NE) ? sg[gb+2] : -1;
      g4[rt].w = (gb+3 < NE) ? sg[gb+3] : -1;
    }
    int gA = sg[min(rb, NE-1)], gB = sg[min(rb+15, NE-1)];
    tok[rt] = (rb + 15 < NE) && (gA == gB);
    gfi[rt] = gA; gla[rt] = gB;
  }
  int gW = sg[min(r0, NE-1)];
  bool wok = (r0 + 31 < NE) && (gW == sg[min(r0+31, NE-1)]);

  const short8* bp0 = (const short8*)(w1eT + (m << 5) + (q << 3));
  short8 b0 = bp0[0];
  float bias = b1e[m];

  for (int nt=0; nt<32; ++nt){
    int ntn = (nt + 1) & 31;
    const short8* np = (const short8*)(w1eT + (((ntn<<4) + m) << 5) + (q << 3));
    short8 pb0 = np[0];
    float pbias = b1e[(ntn<<4) + m];
    float wsum = 0.0f;
#pragma unroll
    for (int rt=0; rt<2; ++rt){
      f32x4 acc = {bias, bias, bias, bias};
      acc = __builtin_amdgcn_mfma_f32_16x16x32_bf16(a0[rt], b0, acc, 0, 0, 0);
      float v0 = gelu_f(acc[0]);
      float v1 = gelu_f(acc[1]);
      float v2 = gelu_f(acc[2]);
      float v3 = gelu_f(acc[3]);
      if (wok){
        wsum += (v0+v1)+(v2+v3);
      } else if (tok[rt]){
        float ts = (v0+v1)+(v2+v3);
        ts += __shfl_xor(ts, 16);
        ts += __shfl_xor(ts, 32);
        if (lane < 16) unsafeAtomicAdd(&S[(size_t)gfi[rt]*1024 + 512 + (nt<<4) + lane], ts);
      } else {
        int gA = gfi[rt], gB = gla[rt];
        float sA = 0.f, sB = 0.f;
        sA += (g4[rt].x==gA)?v0:0.f; sB += (g4[rt].x==gB)?v0:0.f;
        sA += (g4[rt].y==gA)?v1:0.f; sB += (g4[rt].y==gB)?v1:0.f;
        sA += (g4[rt].z==gA)?v2:0.f; sB += (g4[rt].z==gB)?v2:0.f;
        sA += (g4[rt].w==gA)?v3:0.f; sB += (g4[rt].w==gB)?v3:0.f;
        int cb = (nt<<4) + m;
        if (g4[rt].x>=0 && g4[rt].x!=gA && g4[rt].x!=gB) unsafeAtomicAdd(&S[(size_t)g4[rt].x*1024 + 512 + cb], v0);
        if (g4[rt].y>=0 && g4[rt].y!=gA && g4[rt].y!=gB) unsafeAtomicAdd(&S[(size_t)g4[rt].y*1024 + 512 + cb], v1);
        if (g4[rt].z>=0 && g4[rt].z!=gA && g4[rt].z!=gB) unsafeAtomicAdd(&S[(size_t)g4[rt].z*1024 + 512 + cb], v2);
        if (g4[rt].w>=0 && g4[rt].w!=gA && g4[rt].w!=gB) unsafeAtomicAdd(&S[(size_t)g4[rt].w*1024 + 512 + cb], v3);
        sA += __shfl_xor(sA, 16); sA += __shfl_xor(sA, 32);
        sB += __shfl_xor(sB, 16); sB += __shfl_xor(sB, 32);
        if (lane < 16){
          unsafeAtomicAdd(&S[(size_t)gA*1024 + 512 + (nt<<4) + lane], sA);
          unsafeAtomicAdd(&S[(size_t)gB*1024 + 512 + (nt<<4) + lane], sB);
        }
      }
    }
    if (wok){
      wsum += __shfl_xor(wsum, 16);
      wsum += __shfl_xor(wsum, 32);
      if (lane < 16) unsafeAtomicAdd(&S[(size_t)gW*1024 + 512 + (nt<<4) + lane], wsum);
    }
    b0 = pb0; bias = pbias;
  }
}

// ---------------- init gh / y1 / y2 ----------------
__global__ __launch_bounds__(256) void kinit(const float* __restrict__ gf, const int* __restrict__ nstart,
    const int* __restrict__ cnte, const float* __restrict__ b2n, const float* __restrict__ b2e,
    const float* __restrict__ ob1, const float* __restrict__ ob2,
    float* __restrict__ gh, float* __restrict__ y1, float* __restrict__ y2){
  int i = blockIdx.x*256 + threadIdx.x;       // float4 index over 1024*512/4
  int f = i*4;
  int r = f >> 9, c = f & 511;
  float cn = (float)(nstart[r+1] - nstart[r]);
  float ce = (float)cnte[r];
  float4 gv = *(const float4*)&gf[f];
  float4 bn4 = *(const float4*)&b2n[c];
  float4 be4 = *(const float4*)&b2e[c];
  float4 o;
  o.x = gv.x + cn*bn4.x + ce*be4.x;
  o.y = gv.y + cn*bn4.y + ce*be4.y;
  o.z = gv.z + cn*bn4.z + ce*be4.z;
  o.w = gv.w + cn*bn4.w + ce*be4.w;
  *(float4*)&gh[f] = o;
  *(float4*)&y1[f] = *(const float4*)&ob1[c];
  *(float4*)&y2[f] = *(const float4*)&ob2[c];
}

// ---------------- split-K fp32 GEMM, atomic accumulate; optional gelu(bn()) on A ----------------
__global__ __launch_bounds__(256) void kgemm_sk(const float* __restrict__ A, int lda,
    const float* __restrict__ B0, const float* __restrict__ B1, float* __restrict__ out,
    int act, const float* __restrict__ gam, const float* __restrict__ bet){
  __shared__ float Ast[16*68];
  __shared__ float Bs[16*68];
  const int t = threadIdx.x, tx = t & 15, ty = t >> 4;
  const int c0 = blockIdx.x*64, r0 = blockIdx.y*64, kbase = blockIdx.z*256;
  const float rs = 0.99999500003750f;
  float acc[4][4] = {};
  for (int ks=0; ks<16; ++ks){
    const int k0 = kbase + ks*16;
    const float* Bp = (k0 < HH) ? (B0 + (size_t)k0*HH) : (B1 + (size_t)(k0-HH)*HH);
#pragma unroll
    for (int u=0; u<4; ++u){
      int ff = t + u*256;
      int ak = k0 + (ff & 15);
      float av = A[(size_t)(r0 + (ff >> 4))*lda + ak];
      if (act) av = gelu_f(av * (gam[ak]*rs) + bet[ak]);
      Ast[(ff & 15)*68 + (ff >> 4)] = av;
      Bs[(ff >> 6)*68 + (ff & 63)] = Bp[(size_t)(ff >> 6)*HH + c0 + (ff & 63)];
    }
    __syncthreads();
#pragma unroll
    for (int k=0;k<16;++k){
      float4 a4 = *(const float4*)&Ast[k*68 + ty*4];
      float4 b4 = *(const float4*)&Bs[k*68 + tx*4];
      float av[4] = {a4.x, a4.y, a4.z, a4.w};
      float bv[4] = {b4.x, b4.y, b4.z, b4.w};
#pragma unroll
      for (int i=0;i<4;++i)
#pragma unroll
        for (int j=0;j<4;++j) acc[i][j] = __builtin_fmaf(av[i], bv[j], acc[i][j]);
    }
    __syncthreads();
  }
  const int r = r0 + ty*4, c = c0 + tx*4;
#pragma unroll
  for (int i=0;i<4;++i)
#pragma unroll
    for (int j=0;j<4;++j) unsafeAtomicAdd(&out[(size_t)(r+i)*HH + c + j], acc[i][j]);
}

// ---------------- final: x2 = gelu(bn(y2)); out = x2@ow3 + ob3 ----------------
__global__ __launch_bounds__(256) void kfinal(const float* __restrict__ y2, const float* __restrict__ og2,
    const float* __restrict__ obe2, const float* __restrict__ w3, const float* __restrict__ b3,
    float* __restrict__ out){
  const float rs = 0.99999500003750f;
  const int lane = threadIdx.x & 63, wv = threadIdx.x >> 6;
  const int r = blockIdx.x*4 + wv;
  float a0 = 0.f, a1 = 0.f;
#pragma unroll
  for (int tt=0; tt<8; ++tt){
    int k = lane + tt*64;
    float x = gelu_f(y2[(size_t)r*HH + k] * (og2[k]*rs) + obe2[k]);
    a0 = __builtin_fmaf(x, w3[2*k], a0);
    a1 = __builtin_fmaf(x, w3[2*k+1], a1);
  }
#pragma unroll
  for (int d=1; d<64; d<<=1){ a0 += __shfl_xor(a0, d); a1 += __shfl_xor(a1, d); }
  if (lane == 0){ out[r*2] = a0 + b3[0]; out[r*2+1] = a1 + b3[1]; }
}

extern "C" void kernel_launch(void* const* d_in, const int* in_sizes, int n_in,
                              void* d_out, int out_size, void* d_ws, size_t ws_size,
                              hipStream_t stream) {
  const float* nf    = (const float*)d_in[0];
  const float* ef    = (const float*)d_in[1];
  const float* gf    = (const float*)d_in[2];
  const float* dp    = (const float*)d_in[3];
  const int*   ny    = (const int*)d_in[4];
  const int*   bidx  = (const int*)d_in[5];
  const int*   eidx  = (const int*)d_in[6];
  const float* nfw1  = (const float*)d_in[7];
  const float* nfb1  = (const float*)d_in[8];
  const float* nfg1  = (const float*)d_in[9];
  const float* nfbe1 = (const float*)d_in[10];
  const float* w2n   = (const float*)d_in[11];
  const float* b2n   = (const float*)d_in[12];
  const float* efw1  = (const float*)d_in[13];
  const float* efb1  = (const float*)d_in[14];
  const float* efg1  = (const float*)d_in[15];
  const float* efbe1 = (const float*)d_in[16];
  const float* w2e   = (const float*)d_in[17];
  const float* b2e   = (const float*)d_in[18];
  const float* ow1   = (const float*)d_in[19];
  const float* ob1   = (const float*)d_in[20];
  const float* og1   = (const float*)d_in[21];
  const float* obe1  = (const float*)d_in[22];
  const float* ow2   = (const float*)d_in[23];
  const float* ob2   = (const float*)d_in[24];
  const float* og2   = (const float*)d_in[25];
  const float* obe2  = (const float*)d_in[26];
  const float* ow3   = (const float*)d_in[27];
  const float* ob3   = (const float*)d_in[28];

  // workspace carve (S first so one memset covers S+cnte)
  float* S    = (float*)d_ws;                 // 1024 x 1024 (node cols 0-511, edge cols 512-1023)
  int* cnte   = (int*)(S + NG*1024);          // 1024
  int* cursor = cnte + NG;                    // 1024
  int* nstart = cursor + NG;                  // 1025
  int* eg     = nstart + NG + 1;              // NE
  int* perm   = eg + NE;                      // NE
  int* sg     = perm + NE;                    // NE
  unsigned short* w1nT = (unsigned short*)(sg + NE);  // 512*64
  unsigned short* w1eT = w1nT + HH*64;                // 512*32
  float* b1n  = (float*)(w1eT + HH*32);       // 512
  float* b1e  = b1n + HH;                     // 512
  float* gh   = b1e + HH;                     // 1024*512
  float* y1   = gh + NG*HH;                   // 1024*512
  float* y2   = y1 + NG*HH;                   // 1024*512

  hipMemsetAsync(d_ws, 0, (size_t)NG*1024*sizeof(float) + NG*sizeof(int), stream);

  kprep<<<196, 256, 0, stream>>>(nfw1, nfb1, nfg1, nfbe1, efw1, efb1, efg1, efbe1,
                                 w1nT, w1eT, b1n, b1e);
  kbound<<<(NN+255)/256, 256, 0, stream>>>(bidx, nstart);
  khist_edge<<<256, 256, 0, stream>>>(bidx, eidx, eg, cnte);
  kscan<<<1, NG, 0, stream>>>(cnte, cursor);
  kscatter<<<128, 1024, 0, stream>>>(eg, cursor, perm, sg);
  knode<<<(NN+127)/128, 256, 0, stream>>>(nf, dp, ny, bidx, w1nT, b1n, S);
  kedge<<<(NE+127)/128, 256, 0, stream>>>(ef, perm, sg, w1eT, b1e, S);
  kinit<<<NG*HH/(256*4), 256, 0, stream>>>(gf, nstart, cnte, b2n, b2e, ob1, ob2, gh, y1, y2);
  // gh += [Sn|Se] @ [W2n;W2e]   (split-K=4)
  kgemm_sk<<<dim3(8,16,4), 256, 0, stream>>>(S, 1024, w2n, w2e, gh, 0, nullptr, nullptr);
  // y1 += gh @ ow1              (split-K=2)
  kgemm_sk<<<dim3(8,16,2), 256, 0, stream>>>(gh, 512, ow1, ow1, y1, 0, nullptr, nullptr);
  // y2 += gelu(bn(y1)) @ ow2    (split-K=2, activation fused into A-staging)
  kgemm_sk<<<dim3(8,16,2), 256, 0, stream>>>(y1, 512, ow2, ow2, y2, 1, og1, obe1);
  kfinal<<<NG/4, 256, 0, stream>>>(y2, og2, obe2, ow3, ob3, (float*)d_out);
}